// Round 3
// baseline (691.317 us; speedup 1.0000x reference)
//
#include <hip/hip_runtime.h>

#define NN 50000
#define NE 800000
#define NTILE_E 12500

typedef __attribute__((ext_vector_type(8))) short bf16x8;
typedef __attribute__((ext_vector_type(8))) unsigned short us8;
typedef __attribute__((ext_vector_type(4))) unsigned short us4;
typedef __attribute__((ext_vector_type(4))) float f32x4;
typedef __attribute__((ext_vector_type(2))) short s16x2;

#define MFMA16 __builtin_amdgcn_mfma_f32_16x16x32_bf16

__device__ __forceinline__ unsigned short f2b(float f) {
    union { float f; unsigned int u; } x; x.f = f;
    unsigned int r = x.u + 0x7FFFu + ((x.u >> 16) & 1u);
    return (unsigned short)(r >> 16);
}

__device__ __forceinline__ void atomic_pk_bf16(unsigned short* addr, float a, float b) {
    s16x2 v; v[0] = (short)f2b(a); v[1] = (short)f2b(b);
    __builtin_amdgcn_global_atomic_fadd_v2bf16(
        (__attribute__((address_space(1))) s16x2*)(unsigned long long)addr, v);
}

// ---------------- prep: nodes -> bf16; weights -> bf16 transposed [n][k] ----------------
__global__ __launch_bounds__(256) void prep_kernel(
    const float* __restrict__ nodes,
    const float* __restrict__ We1, const float* __restrict__ We2,
    const float* __restrict__ Wn1, const float* __restrict__ Wn2,
    unsigned short* __restrict__ nodes_bf,
    unsigned short* __restrict__ We1T, unsigned short* __restrict__ We2T,
    unsigned short* __restrict__ Wn1T, unsigned short* __restrict__ Wn2T)
{
    const int b = blockIdx.x, t = threadIdx.x;
    if (b < 400) {
        const float4* src = (const float4*)nodes;
        for (int i = b * 256 + t; i < NN * 16; i += 400 * 256) {
            float4 v = src[i];
            us4 o; o[0] = f2b(v.x); o[1] = f2b(v.y); o[2] = f2b(v.z); o[3] = f2b(v.w);
            *(us4*)&nodes_bf[(size_t)i * 4] = o;
        }
    } else {
        const int base = (b - 400) * 256 + t;
        for (int idx = base; idx < 57344; idx += 16 * 256) {
            if (idx < 24576) {               // We1T[128][192]
                int n = idx / 192, k = idx % 192;
                We1T[idx] = f2b(We1[k * 128 + n]);
            } else if (idx < 32768) {        // We2T[64][128]
                int j = idx - 24576; int n = j / 128, k = j % 128;
                We2T[j] = f2b(We2[k * 64 + n]);
            } else if (idx < 49152) {        // Wn1T[128][128]
                int j = idx - 32768; int n = j / 128, k = j % 128;
                Wn1T[j] = f2b(Wn1[k * 128 + n]);
            } else {                         // Wn2T[64][128]
                int j = idx - 49152; int n = j / 128, k = j % 128;
                Wn2T[j] = f2b(Wn2[k * 64 + n]);
            }
        }
    }
}

// ---------------- edge kernel: 64 edges/tile, 4 tiles/block, 2 barriers/tile ----------------
__global__ __launch_bounds__(256, 4) void edge_kernel(
    const unsigned short* __restrict__ nodes_bf, const float* __restrict__ edges,
    const unsigned short* __restrict__ We1T, const float* __restrict__ be1,
    const unsigned short* __restrict__ We2T, const float* __restrict__ be2,
    const int* __restrict__ senders, const int* __restrict__ receivers,
    unsigned short* __restrict__ agg)
{
    __shared__ unsigned short hs[64 * 136];   // 17408 B, GEMM1 out / GEMM2 B
    __shared__ unsigned short w2[64 * 136];   // We2T staged once per block

    const int t = threadIdx.x;
    const int w = t >> 6, l = t & 63, lc = l & 15, lq = l >> 4;

    // stage We2T -> LDS (stride 136 to break bank aliasing)
    #pragma unroll
    for (int i = 0; i < 4; ++i) {
        int idx = t + 256 * i;               // 0..1023 us8
        int n = idx >> 4, q = idx & 15;
        *(us8*)&w2[n * 136 + q * 8] = *(const us8*)&We2T[n * 128 + q * 8];
    }

    // register-resident GEMM1 B-frags: wave w owns N cols [w*32, w*32+32)
    bf16x8 b1[6][2];
    #pragma unroll
    for (int c = 0; c < 6; ++c)
        #pragma unroll
        for (int j = 0; j < 2; ++j)
            b1[c][j] = *(const bf16x8*)&We1T[(size_t)(w * 32 + j * 16 + lc) * 192 + c * 32 + lq * 8];
    const float be1a = be1[w * 32 + lc];
    const float be1b = be1[w * 32 + 16 + lc];

    __syncthreads();

    for (int tile = blockIdx.x; tile < NTILE_E; tile += gridDim.x) {
        const int e0 = tile * 64;
        int rn[4], sn[4];
        #pragma unroll
        for (int mt = 0; mt < 4; ++mt) {
            rn[mt] = receivers[e0 + mt * 16 + lc];
            sn[mt] = senders[e0 + mt * 16 + lc];
        }

        // GEMM1: A-frags straight from global (L2), B from registers. No barriers.
        f32x4 acc0[4], acc1v[4];
        #pragma unroll
        for (int mt = 0; mt < 4; ++mt) { acc0[mt] = (f32x4)0.f; acc1v[mt] = (f32x4)0.f; }

        #pragma unroll
        for (int mt = 0; mt < 4; ++mt) {
            const float* ep = &edges[(size_t)(e0 + mt * 16 + lc) * 64 + lq * 8];
            #pragma unroll
            for (int c = 0; c < 2; ++c) {
                float4 p0 = *(const float4*)(ep + c * 32);
                float4 p1 = *(const float4*)(ep + c * 32 + 4);
                us8 u; u[0] = f2b(p0.x); u[1] = f2b(p0.y); u[2] = f2b(p0.z); u[3] = f2b(p0.w);
                       u[4] = f2b(p1.x); u[5] = f2b(p1.y); u[6] = f2b(p1.z); u[7] = f2b(p1.w);
                bf16x8 af = (bf16x8)u;
                acc0[mt]  = MFMA16(af, b1[c][0], acc0[mt], 0, 0, 0);
                acc1v[mt] = MFMA16(af, b1[c][1], acc1v[mt], 0, 0, 0);
            }
            const unsigned short* rp = &nodes_bf[(size_t)rn[mt] * 64 + lq * 8];
            #pragma unroll
            for (int c = 0; c < 2; ++c) {
                bf16x8 af = *(const bf16x8*)(rp + c * 32);
                acc0[mt]  = MFMA16(af, b1[2 + c][0], acc0[mt], 0, 0, 0);
                acc1v[mt] = MFMA16(af, b1[2 + c][1], acc1v[mt], 0, 0, 0);
            }
            const unsigned short* sp = &nodes_bf[(size_t)sn[mt] * 64 + lq * 8];
            #pragma unroll
            for (int c = 0; c < 2; ++c) {
                bf16x8 af = *(const bf16x8*)(sp + c * 32);
                acc0[mt]  = MFMA16(af, b1[4 + c][0], acc0[mt], 0, 0, 0);
                acc1v[mt] = MFMA16(af, b1[4 + c][1], acc1v[mt], 0, 0, 0);
            }
        }

        __syncthreads();   // prior tile's GEMM2 hs reads are drained
        #pragma unroll
        for (int mt = 0; mt < 4; ++mt)
            #pragma unroll
            for (int r = 0; r < 4; ++r) {
                int row = mt * 16 + lq * 4 + r;
                hs[row * 136 + w * 32 + lc]      = f2b(fmaxf(acc0[mt][r] + be1a, 0.f));
                hs[row * 136 + w * 32 + 16 + lc] = f2b(fmaxf(acc1v[mt][r] + be1b, 0.f));
            }
        __syncthreads();

        // GEMM2 transposed: D2[n2][m] = We2T[n2][k] @ hs[m][k]^T; wave owns m in [w*16, w*16+16)
        f32x4 acc2[4];
        #pragma unroll
        for (int nt = 0; nt < 4; ++nt) acc2[nt] = (f32x4)0.f;
        #pragma unroll
        for (int c = 0; c < 4; ++c) {
            bf16x8 bf = *(const bf16x8*)&hs[(w * 16 + lc) * 136 + c * 32 + lq * 8];
            #pragma unroll
            for (int nt = 0; nt < 4; ++nt) {
                bf16x8 af = *(const bf16x8*)&w2[(nt * 16 + lc) * 136 + c * 32 + lq * 8];
                acc2[nt] = MFMA16(af, bf, acc2[nt], 0, 0, 0);
            }
        }

        // scatter: lane = one node row, 16 consecutive cols -> packed bf16 atomics
        const int node = rn[w];               // = receivers[e0 + w*16 + lc]
        unsigned short* ap = &agg[(size_t)node * 64];
        #pragma unroll
        for (int nt = 0; nt < 4; ++nt) {
            int col = nt * 16 + lq * 4;
            float4 bias = *(const float4*)&be2[col];
            atomic_pk_bf16(ap + col,     acc2[nt][0] + bias.x, acc2[nt][1] + bias.y);
            atomic_pk_bf16(ap + col + 2, acc2[nt][2] + bias.z, acc2[nt][3] + bias.w);
        }
    }
}

// ---------------- node kernel: 64 nodes/block ----------------
__global__ __launch_bounds__(256, 4) void node_kernel(
    const unsigned short* __restrict__ nodes_bf, const unsigned short* __restrict__ agg,
    const unsigned short* __restrict__ Wn1T, const float* __restrict__ bn1,
    const unsigned short* __restrict__ Wn2T, const float* __restrict__ bn2,
    float* __restrict__ out)
{
    __shared__ unsigned short hs[64 * 136];
    __shared__ unsigned short w2[64 * 136];

    const int t = threadIdx.x;
    const int w = t >> 6, l = t & 63, lc = l & 15, lq = l >> 4;
    const int n0 = blockIdx.x * 64;

    #pragma unroll
    for (int i = 0; i < 4; ++i) {
        int idx = t + 256 * i;
        int n = idx >> 4, q = idx & 15;
        *(us8*)&w2[n * 136 + q * 8] = *(const us8*)&Wn2T[n * 128 + q * 8];
    }

    bf16x8 b1[4][2];
    #pragma unroll
    for (int c = 0; c < 4; ++c)
        #pragma unroll
        for (int j = 0; j < 2; ++j)
            b1[c][j] = *(const bf16x8*)&Wn1T[(size_t)(w * 32 + j * 16 + lc) * 128 + c * 32 + lq * 8];
    const float bn1a = bn1[w * 32 + lc];
    const float bn1b = bn1[w * 32 + 16 + lc];

    __syncthreads();

    f32x4 acc0[4], acc1v[4];
    #pragma unroll
    for (int mt = 0; mt < 4; ++mt) { acc0[mt] = (f32x4)0.f; acc1v[mt] = (f32x4)0.f; }

    #pragma unroll
    for (int mt = 0; mt < 4; ++mt) {
        int row = n0 + mt * 16 + lc;
        bool ok = row < NN;
        const unsigned short* apz = &agg[(size_t)row * 64 + lq * 8];
        const unsigned short* npz = &nodes_bf[(size_t)row * 64 + lq * 8];
        #pragma unroll
        for (int c = 0; c < 2; ++c) {
            us8 z = {0,0,0,0,0,0,0,0};
            bf16x8 af = ok ? *(const bf16x8*)(apz + c * 32) : (bf16x8)z;
            acc0[mt]  = MFMA16(af, b1[c][0], acc0[mt], 0, 0, 0);
            acc1v[mt] = MFMA16(af, b1[c][1], acc1v[mt], 0, 0, 0);
        }
        #pragma unroll
        for (int c = 0; c < 2; ++c) {
            us8 z = {0,0,0,0,0,0,0,0};
            bf16x8 af = ok ? *(const bf16x8*)(npz + c * 32) : (bf16x8)z;
            acc0[mt]  = MFMA16(af, b1[2 + c][0], acc0[mt], 0, 0, 0);
            acc1v[mt] = MFMA16(af, b1[2 + c][1], acc1v[mt], 0, 0, 0);
        }
    }

    #pragma unroll
    for (int mt = 0; mt < 4; ++mt)
        #pragma unroll
        for (int r = 0; r < 4; ++r) {
            int row = mt * 16 + lq * 4 + r;
            hs[row * 136 + w * 32 + lc]      = f2b(fmaxf(acc0[mt][r] + bn1a, 0.f));
            hs[row * 136 + w * 32 + 16 + lc] = f2b(fmaxf(acc1v[mt][r] + bn1b, 0.f));
        }
    __syncthreads();

    f32x4 acc2[4];
    #pragma unroll
    for (int nt = 0; nt < 4; ++nt) acc2[nt] = (f32x4)0.f;
    #pragma unroll
    for (int c = 0; c < 4; ++c) {
        bf16x8 bf = *(const bf16x8*)&hs[(w * 16 + lc) * 136 + c * 32 + lq * 8];
        #pragma unroll
        for (int nt = 0; nt < 4; ++nt) {
            bf16x8 af = *(const bf16x8*)&w2[(nt * 16 + lc) * 136 + c * 32 + lq * 8];
            acc2[nt] = MFMA16(af, bf, acc2[nt], 0, 0, 0);
        }
    }

    const int row = n0 + w * 16 + lc;
    if (row < NN) {
        float* op = &out[(size_t)row * 64];
        #pragma unroll
        for (int nt = 0; nt < 4; ++nt) {
            int col = nt * 16 + lq * 4;
            float4 bias = *(const float4*)&bn2[col];
            float4 v;
            v.x = acc2[nt][0] + bias.x; v.y = acc2[nt][1] + bias.y;
            v.z = acc2[nt][2] + bias.z; v.w = acc2[nt][3] + bias.w;
            *(float4*)(op + col) = v;
        }
    }
}

extern "C" void kernel_launch(void* const* d_in, const int* in_sizes, int n_in,
                              void* d_out, int out_size, void* d_ws, size_t ws_size,
                              hipStream_t stream) {
    const float* nodes = (const float*)d_in[0];
    const float* edges = (const float*)d_in[1];
    const float* We1   = (const float*)d_in[2];
    const float* be1   = (const float*)d_in[3];
    const float* We2   = (const float*)d_in[4];
    const float* be2   = (const float*)d_in[5];
    const float* Wn1   = (const float*)d_in[6];
    const float* bn1   = (const float*)d_in[7];
    const float* Wn2   = (const float*)d_in[8];
    const float* bn2   = (const float*)d_in[9];
    const int* senders   = (const int*)d_in[10];
    const int* receivers = (const int*)d_in[11];
    float* out = (float*)d_out;

    char* ws = (char*)d_ws;
    unsigned short* agg      = (unsigned short*)ws;              // 6,400,000 B (bf16)
    unsigned short* nodes_bf = (unsigned short*)(ws + 6400000);  // 6,400,000 B
    unsigned short* We1T = (unsigned short*)(ws + 12800000);     //    49,152 B
    unsigned short* We2T = (unsigned short*)(ws + 12849152);     //    16,384 B
    unsigned short* Wn1T = (unsigned short*)(ws + 12865536);     //    32,768 B
    unsigned short* Wn2T = (unsigned short*)(ws + 12898304);     //    16,384 B

    hipMemsetAsync(agg, 0, (size_t)NN * 64 * sizeof(unsigned short), stream);
    prep_kernel<<<416, 256, 0, stream>>>(nodes, We1, We2, Wn1, Wn2,
                                         nodes_bf, We1T, We2T, Wn1T, Wn2T);
    edge_kernel<<<3125, 256, 0, stream>>>(nodes_bf, edges, We1T, be1, We2T, be2,
                                          senders, receivers, agg);
    node_kernel<<<782, 256, 0, stream>>>(nodes_bf, agg, Wn1T, bn1, Wn2T, bn2, out);
}

// Round 4
// 597.531 us; speedup vs baseline: 1.1570x; 1.1570x over previous
//
#include <hip/hip_runtime.h>

#define NN 50000
#define NE 800000

typedef __attribute__((ext_vector_type(8))) short bf16x8;
typedef __attribute__((ext_vector_type(8))) unsigned short us8;
typedef __attribute__((ext_vector_type(4))) unsigned short us4;
typedef __attribute__((ext_vector_type(4))) float f32x4;
typedef __attribute__((ext_vector_type(2))) short s16x2;

#define MFMA16 __builtin_amdgcn_mfma_f32_16x16x32_bf16

__device__ __forceinline__ unsigned short f2b(float f) {
    union { float f; unsigned int u; } x; x.f = f;
    unsigned int r = x.u + 0x7FFFu + ((x.u >> 16) & 1u);
    return (unsigned short)(r >> 16);
}

__device__ __forceinline__ void atomic_pk_bf16(unsigned short* addr, float a, float b) {
    s16x2 v; v[0] = (short)f2b(a); v[1] = (short)f2b(b);
    __builtin_amdgcn_global_atomic_fadd_v2bf16(
        (__attribute__((address_space(1))) s16x2*)(unsigned long long)addr, v);
}

// ---------------- prep: nodes -> bf16; weights -> bf16 transposed [n][k] ----------------
__global__ __launch_bounds__(256) void prep_kernel(
    const float* __restrict__ nodes,
    const float* __restrict__ We1, const float* __restrict__ We2,
    const float* __restrict__ Wn1, const float* __restrict__ Wn2,
    unsigned short* __restrict__ nodes_bf,
    unsigned short* __restrict__ We1T, unsigned short* __restrict__ We2T,
    unsigned short* __restrict__ Wn1T, unsigned short* __restrict__ Wn2T)
{
    const int b = blockIdx.x, t = threadIdx.x;
    if (b < 400) {
        const float4* src = (const float4*)nodes;
        for (int i = b * 256 + t; i < NN * 16; i += 400 * 256) {
            float4 v = src[i];
            us4 o; o[0] = f2b(v.x); o[1] = f2b(v.y); o[2] = f2b(v.z); o[3] = f2b(v.w);
            *(us4*)&nodes_bf[(size_t)i * 4] = o;
        }
    } else {
        const int base = (b - 400) * 256 + t;
        for (int idx = base; idx < 57344; idx += 16 * 256) {
            if (idx < 24576) {               // We1T[128][192]
                int n = idx / 192, k = idx % 192;
                We1T[idx] = f2b(We1[k * 128 + n]);
            } else if (idx < 32768) {        // We2T[64][128]
                int j = idx - 24576; int n = j / 128, k = j % 128;
                We2T[j] = f2b(We2[k * 64 + n]);
            } else if (idx < 49152) {        // Wn1T[128][128]
                int j = idx - 32768; int n = j / 128, k = j % 128;
                Wn1T[j] = f2b(Wn1[k * 128 + n]);
            } else {                         // Wn2T[64][128]
                int j = idx - 49152; int n = j / 128, k = j % 128;
                Wn2T[j] = f2b(Wn2[k * 64 + n]);
            }
        }
    }
}

// ---------------- edge kernel: 64 edges/block, 4 waves, 4 barriers ----------------
// xs[64][200]: gathered [edge|recv|send] bf16 (192 valid); after GEMM1, hs
// aliases the same buffer with stride 136. We1T B-frags register-resident;
// We2T staged once into w2. GEMM2 transposed; packed bf16 atomics scatter.
__global__ __launch_bounds__(256, 3) void edge_kernel(
    const unsigned short* __restrict__ nodes_bf, const float* __restrict__ edges,
    const unsigned short* __restrict__ We1T, const float* __restrict__ be1,
    const unsigned short* __restrict__ We2T, const float* __restrict__ be2,
    const int* __restrict__ senders, const int* __restrict__ receivers,
    unsigned short* __restrict__ agg)
{
    __shared__ unsigned short xs[64 * 200];   // 25600 B (hs aliases, stride 136)
    __shared__ unsigned short w2[64 * 136];   // 17408 B
    __shared__ int ridx[64];
    __shared__ int sidx[64];

    const int t = threadIdx.x;
    const int e0 = blockIdx.x * 64;
    const int w = t >> 6, l = t & 63, lc = l & 15, lq = l >> 4;

    if (t < 64) { ridx[t] = receivers[e0 + t]; sidx[t] = senders[e0 + t]; }

    // stage We2T once (independent of indices)
    #pragma unroll
    for (int i = 0; i < 4; ++i) {
        int idx = t + 256 * i;               // 0..1023 us8
        int n = idx >> 4, q = idx & 15;
        *(us8*)&w2[n * 136 + q * 8] = *(const us8*)&We2T[n * 128 + q * 8];
    }

    // register-resident GEMM1 B-frags: wave w owns N cols [w*32, w*32+32)
    bf16x8 b1[6][2];
    #pragma unroll
    for (int c = 0; c < 6; ++c)
        #pragma unroll
        for (int j = 0; j < 2; ++j)
            b1[c][j] = *(const bf16x8*)&We1T[(size_t)(w * 32 + j * 16 + lc) * 192 + c * 32 + lq * 8];
    const float be1a = be1[w * 32 + lc];
    const float be1b = be1[w * 32 + 16 + lc];

    __syncthreads();   // indices visible

    // cooperative gather: edges fp32->bf16 (4 float4/thread)
    #pragma unroll
    for (int i = 0; i < 4; ++i) {
        int idx = t + 256 * i;               // 0..1023
        int m = idx >> 4, q = idx & 15;
        float4 v = *(const float4*)&edges[((size_t)(e0 + m)) * 64 + q * 4];
        us4 o; o[0] = f2b(v.x); o[1] = f2b(v.y); o[2] = f2b(v.z); o[3] = f2b(v.w);
        *(us4*)&xs[m * 200 + q * 4] = o;
    }
    // receiver rows (2 us8/thread)
    #pragma unroll
    for (int i = 0; i < 2; ++i) {
        int idx = t + 256 * i;               // 0..511
        int m = idx >> 3, q = idx & 7;
        *(us8*)&xs[m * 200 + 64 + q * 8] = *(const us8*)&nodes_bf[(size_t)ridx[m] * 64 + q * 8];
    }
    // sender rows (2 us8/thread)
    #pragma unroll
    for (int i = 0; i < 2; ++i) {
        int idx = t + 256 * i;
        int m = idx >> 3, q = idx & 7;
        *(us8*)&xs[m * 200 + 128 + q * 8] = *(const us8*)&nodes_bf[(size_t)sidx[m] * 64 + q * 8];
    }
    __syncthreads();

    // GEMM1: [64,192] @ We1[192,128], B in registers, no barriers
    f32x4 acc0[4], acc1v[4];
    #pragma unroll
    for (int mt = 0; mt < 4; ++mt) { acc0[mt] = (f32x4)0.f; acc1v[mt] = (f32x4)0.f; }

    #pragma unroll
    for (int c = 0; c < 6; ++c) {
        #pragma unroll
        for (int mt = 0; mt < 4; ++mt) {
            bf16x8 a = *(const bf16x8*)&xs[(mt * 16 + lc) * 200 + c * 32 + lq * 8];
            acc0[mt]  = MFMA16(a, b1[c][0], acc0[mt], 0, 0, 0);
            acc1v[mt] = MFMA16(a, b1[c][1], acc1v[mt], 0, 0, 0);
        }
    }

    __syncthreads();   // all xs reads done before aliasing as hs

    unsigned short* hs = xs;   // stride 136 now
    #pragma unroll
    for (int mt = 0; mt < 4; ++mt)
        #pragma unroll
        for (int r = 0; r < 4; ++r) {
            int row = mt * 16 + lq * 4 + r;
            hs[row * 136 + w * 32 + lc]      = f2b(fmaxf(acc0[mt][r] + be1a, 0.f));
            hs[row * 136 + w * 32 + 16 + lc] = f2b(fmaxf(acc1v[mt][r] + be1b, 0.f));
        }
    __syncthreads();

    // GEMM2 transposed: D2[n2][m] = We2T[n2][:] . hs[m][:]; wave owns m in [w*16, w*16+16)
    f32x4 acc2[4];
    #pragma unroll
    for (int nt = 0; nt < 4; ++nt) acc2[nt] = (f32x4)0.f;
    #pragma unroll
    for (int c = 0; c < 4; ++c) {
        bf16x8 bf = *(const bf16x8*)&hs[(w * 16 + lc) * 136 + c * 32 + lq * 8];
        #pragma unroll
        for (int nt = 0; nt < 4; ++nt) {
            bf16x8 af = *(const bf16x8*)&w2[(nt * 16 + lc) * 136 + c * 32 + lq * 8];
            acc2[nt] = MFMA16(af, bf, acc2[nt], 0, 0, 0);
        }
    }

    // scatter: lane = one edge row (w*16+lc), 16 consecutive cols -> packed bf16 atomics
    const int node = ridx[w * 16 + lc];
    unsigned short* ap = &agg[(size_t)node * 64];
    #pragma unroll
    for (int nt = 0; nt < 4; ++nt) {
        int col = nt * 16 + lq * 4;
        float4 bias = *(const float4*)&be2[col];
        atomic_pk_bf16(ap + col,     acc2[nt][0] + bias.x, acc2[nt][1] + bias.y);
        atomic_pk_bf16(ap + col + 2, acc2[nt][2] + bias.z, acc2[nt][3] + bias.w);
    }
}

// ---------------- node kernel: 64 nodes/block, cooperative stage, 3 barriers ----------------
__global__ __launch_bounds__(256, 4) void node_kernel(
    const unsigned short* __restrict__ nodes_bf, const unsigned short* __restrict__ agg,
    const unsigned short* __restrict__ Wn1T, const float* __restrict__ bn1,
    const unsigned short* __restrict__ Wn2T, const float* __restrict__ bn2,
    float* __restrict__ out)
{
    __shared__ unsigned short xs[64 * 136];   // [agg|node] input, then hs (stride 136)
    __shared__ unsigned short w2[64 * 136];

    const int t = threadIdx.x;
    const int n0 = blockIdx.x * 64;
    const int w = t >> 6, l = t & 63, lc = l & 15, lq = l >> 4;

    #pragma unroll
    for (int i = 0; i < 4; ++i) {
        int idx = t + 256 * i;
        int n = idx >> 4, q = idx & 15;
        *(us8*)&w2[n * 136 + q * 8] = *(const us8*)&Wn2T[n * 128 + q * 8];
    }

    bf16x8 b1[4][2];
    #pragma unroll
    for (int c = 0; c < 4; ++c)
        #pragma unroll
        for (int j = 0; j < 2; ++j)
            b1[c][j] = *(const bf16x8*)&Wn1T[(size_t)(w * 32 + j * 16 + lc) * 128 + c * 32 + lq * 8];
    const float bn1a = bn1[w * 32 + lc];
    const float bn1b = bn1[w * 32 + 16 + lc];

    // cooperative stage: agg rows (cols 0..63) + node rows (cols 64..127)
    us8 z = {0,0,0,0,0,0,0,0};
    #pragma unroll
    for (int i = 0; i < 2; ++i) {
        int idx = t + 256 * i;               // 0..511
        int m = idx >> 3, q = idx & 7;
        int n = n0 + m;
        us8 v = (n < NN) ? *(const us8*)&agg[(size_t)n * 64 + q * 8] : z;
        *(us8*)&xs[m * 136 + q * 8] = v;
    }
    #pragma unroll
    for (int i = 0; i < 2; ++i) {
        int idx = t + 256 * i;
        int m = idx >> 3, q = idx & 7;
        int n = n0 + m;
        us8 v = (n < NN) ? *(const us8*)&nodes_bf[(size_t)n * 64 + q * 8] : z;
        *(us8*)&xs[m * 136 + 64 + q * 8] = v;
    }
    __syncthreads();

    f32x4 acc0[4], acc1v[4];
    #pragma unroll
    for (int mt = 0; mt < 4; ++mt) { acc0[mt] = (f32x4)0.f; acc1v[mt] = (f32x4)0.f; }

    #pragma unroll
    for (int c = 0; c < 4; ++c) {
        #pragma unroll
        for (int mt = 0; mt < 4; ++mt) {
            bf16x8 a = *(const bf16x8*)&xs[(mt * 16 + lc) * 136 + c * 32 + lq * 8];
            acc0[mt]  = MFMA16(a, b1[c][0], acc0[mt], 0, 0, 0);
            acc1v[mt] = MFMA16(a, b1[c][1], acc1v[mt], 0, 0, 0);
        }
    }
    __syncthreads();

    unsigned short* hs = xs;
    #pragma unroll
    for (int mt = 0; mt < 4; ++mt)
        #pragma unroll
        for (int r = 0; r < 4; ++r) {
            int row = mt * 16 + lq * 4 + r;
            hs[row * 136 + w * 32 + lc]      = f2b(fmaxf(acc0[mt][r] + bn1a, 0.f));
            hs[row * 136 + w * 32 + 16 + lc] = f2b(fmaxf(acc1v[mt][r] + bn1b, 0.f));
        }
    __syncthreads();

    f32x4 acc2[4];
    #pragma unroll
    for (int nt = 0; nt < 4; ++nt) acc2[nt] = (f32x4)0.f;
    #pragma unroll
    for (int c = 0; c < 4; ++c) {
        bf16x8 bf = *(const bf16x8*)&hs[(w * 16 + lc) * 136 + c * 32 + lq * 8];
        #pragma unroll
        for (int nt = 0; nt < 4; ++nt) {
            bf16x8 af = *(const bf16x8*)&w2[(nt * 16 + lc) * 136 + c * 32 + lq * 8];
            acc2[nt] = MFMA16(af, bf, acc2[nt], 0, 0, 0);
        }
    }

    const int row = n0 + w * 16 + lc;
    if (row < NN) {
        float* op = &out[(size_t)row * 64];
        #pragma unroll
        for (int nt = 0; nt < 4; ++nt) {
            int col = nt * 16 + lq * 4;
            float4 bias = *(const float4*)&bn2[col];
            float4 v;
            v.x = acc2[nt][0] + bias.x; v.y = acc2[nt][1] + bias.y;
            v.z = acc2[nt][2] + bias.z; v.w = acc2[nt][3] + bias.w;
            *(float4*)(op + col) = v;
        }
    }
}

extern "C" void kernel_launch(void* const* d_in, const int* in_sizes, int n_in,
                              void* d_out, int out_size, void* d_ws, size_t ws_size,
                              hipStream_t stream) {
    const float* nodes = (const float*)d_in[0];
    const float* edges = (const float*)d_in[1];
    const float* We1   = (const float*)d_in[2];
    const float* be1   = (const float*)d_in[3];
    const float* We2   = (const float*)d_in[4];
    const float* be2   = (const float*)d_in[5];
    const float* Wn1   = (const float*)d_in[6];
    const float* bn1   = (const float*)d_in[7];
    const float* Wn2   = (const float*)d_in[8];
    const float* bn2   = (const float*)d_in[9];
    const int* senders   = (const int*)d_in[10];
    const int* receivers = (const int*)d_in[11];
    float* out = (float*)d_out;

    char* ws = (char*)d_ws;
    unsigned short* agg      = (unsigned short*)ws;              // 6,400,000 B (bf16)
    unsigned short* nodes_bf = (unsigned short*)(ws + 6400000);  // 6,400,000 B
    unsigned short* We1T = (unsigned short*)(ws + 12800000);     //    49,152 B
    unsigned short* We2T = (unsigned short*)(ws + 12849152);     //    16,384 B
    unsigned short* Wn1T = (unsigned short*)(ws + 12865536);     //    32,768 B
    unsigned short* Wn2T = (unsigned short*)(ws + 12898304);     //    16,384 B

    hipMemsetAsync(agg, 0, (size_t)NN * 64 * sizeof(unsigned short), stream);
    prep_kernel<<<416, 256, 0, stream>>>(nodes, We1, We2, Wn1, Wn2,
                                         nodes_bf, We1T, We2T, Wn1T, Wn2T);
    edge_kernel<<<NE / 64, 256, 0, stream>>>(nodes_bf, edges, We1T, be1, We2T, be2,
                                             senders, receivers, agg);
    node_kernel<<<(NN + 63) / 64, 256, 0, stream>>>(nodes_bf, agg, Wn1T, bn1, Wn2T, bn2, out);
}

// Round 5
// 482.292 us; speedup vs baseline: 1.4334x; 1.2389x over previous
//
#include <hip/hip_runtime.h>

#define NN 50000
#define NE 800000

typedef __attribute__((ext_vector_type(8))) short bf16x8;
typedef __attribute__((ext_vector_type(8))) unsigned short us8;
typedef __attribute__((ext_vector_type(4))) unsigned short us4;
typedef __attribute__((ext_vector_type(4))) float f32x4;

#define MFMA16 __builtin_amdgcn_mfma_f32_16x16x32_bf16

__device__ __forceinline__ unsigned short f2b(float f) {
    union { float f; unsigned int u; } x; x.f = f;
    unsigned int r = x.u + 0x7FFFu + ((x.u >> 16) & 1u);
    return (unsigned short)(r >> 16);
}

// ---------------- prep: nodes -> bf16; weights -> bf16 transposed [n][k] ----------------
__global__ __launch_bounds__(256) void prep_kernel(
    const float* __restrict__ nodes,
    const float* __restrict__ We1, const float* __restrict__ We2,
    const float* __restrict__ Wn1, const float* __restrict__ Wn2,
    unsigned short* __restrict__ nodes_bf,
    unsigned short* __restrict__ We1T, unsigned short* __restrict__ We2T,
    unsigned short* __restrict__ Wn1T, unsigned short* __restrict__ Wn2T)
{
    const int b = blockIdx.x, t = threadIdx.x;
    if (b < 400) {
        const float4* src = (const float4*)nodes;
        for (int i = b * 256 + t; i < NN * 16; i += 400 * 256) {
            float4 v = src[i];
            us4 o; o[0] = f2b(v.x); o[1] = f2b(v.y); o[2] = f2b(v.z); o[3] = f2b(v.w);
            *(us4*)&nodes_bf[(size_t)i * 4] = o;
        }
    } else {
        const int base = (b - 400) * 256 + t;
        for (int idx = base; idx < 57344; idx += 16 * 256) {
            if (idx < 24576) {               // We1T[128][192]
                int n = idx / 192, k = idx % 192;
                We1T[idx] = f2b(We1[k * 128 + n]);
            } else if (idx < 32768) {        // We2T[64][128]
                int j = idx - 24576; int n = j / 128, k = j % 128;
                We2T[j] = f2b(We2[k * 64 + n]);
            } else if (idx < 49152) {        // Wn1T[128][128]
                int j = idx - 32768; int n = j / 128, k = j % 128;
                Wn1T[j] = f2b(Wn1[k * 128 + n]);
            } else {                         // Wn2T[64][128]
                int j = idx - 49152; int n = j / 128, k = j % 128;
                Wn2T[j] = f2b(Wn2[k * 64 + n]);
            }
        }
    }
}

// ---------------- edge kernel: 64 edges/block, 4 waves, 4 barriers, fp32 scatter ----------------
__global__ __launch_bounds__(256, 4) void edge_kernel(
    const unsigned short* __restrict__ nodes_bf, const float* __restrict__ edges,
    const unsigned short* __restrict__ We1T, const float* __restrict__ be1,
    const unsigned short* __restrict__ We2T, const float* __restrict__ be2,
    const int* __restrict__ senders, const int* __restrict__ receivers,
    float* __restrict__ agg)
{
    __shared__ unsigned short xs[64 * 200];   // 25600 B; hs aliases (stride 136)
    __shared__ int ridx[64];
    __shared__ int sidx[64];

    const int t = threadIdx.x;
    const int e0 = blockIdx.x * 64;
    const int w = t >> 6, l = t & 63, lc = l & 15, lq = l >> 4;

    if (t < 64) { ridx[t] = receivers[e0 + t]; sidx[t] = senders[e0 + t]; }

    // GEMM1 B-frags: wave w owns N cols [w*32, w*32+32)
    bf16x8 b1[6][2];
    #pragma unroll
    for (int c = 0; c < 6; ++c)
        #pragma unroll
        for (int j = 0; j < 2; ++j)
            b1[c][j] = *(const bf16x8*)&We1T[(size_t)(w * 32 + j * 16 + lc) * 192 + c * 32 + lq * 8];
    const float be1a = be1[w * 32 + lc];
    const float be1b = be1[w * 32 + 16 + lc];

    __syncthreads();   // indices visible

    // cooperative gather: edges fp32->bf16 (4 float4/thread)
    #pragma unroll
    for (int i = 0; i < 4; ++i) {
        int idx = t + 256 * i;               // 0..1023
        int m = idx >> 4, q = idx & 15;
        float4 v = *(const float4*)&edges[((size_t)(e0 + m)) * 64 + q * 4];
        us4 o; o[0] = f2b(v.x); o[1] = f2b(v.y); o[2] = f2b(v.z); o[3] = f2b(v.w);
        *(us4*)&xs[m * 200 + q * 4] = o;
    }
    // receiver rows (2 us8/thread)
    #pragma unroll
    for (int i = 0; i < 2; ++i) {
        int idx = t + 256 * i;               // 0..511
        int m = idx >> 3, q = idx & 7;
        *(us8*)&xs[m * 200 + 64 + q * 8] = *(const us8*)&nodes_bf[(size_t)ridx[m] * 64 + q * 8];
    }
    // sender rows (2 us8/thread)
    #pragma unroll
    for (int i = 0; i < 2; ++i) {
        int idx = t + 256 * i;
        int m = idx >> 3, q = idx & 7;
        *(us8*)&xs[m * 200 + 128 + q * 8] = *(const us8*)&nodes_bf[(size_t)sidx[m] * 64 + q * 8];
    }
    __syncthreads();

    // GEMM1: [64,192] @ We1[192,128], B in registers
    f32x4 acc0[4], acc1v[4];
    #pragma unroll
    for (int mt = 0; mt < 4; ++mt) { acc0[mt] = (f32x4)0.f; acc1v[mt] = (f32x4)0.f; }

    #pragma unroll
    for (int c = 0; c < 6; ++c) {
        #pragma unroll
        for (int mt = 0; mt < 4; ++mt) {
            bf16x8 a = *(const bf16x8*)&xs[(mt * 16 + lc) * 200 + c * 32 + lq * 8];
            acc0[mt]  = MFMA16(a, b1[c][0], acc0[mt], 0, 0, 0);
            acc1v[mt] = MFMA16(a, b1[c][1], acc1v[mt], 0, 0, 0);
        }
    }

    __syncthreads();   // all xs reads done before aliasing as hs

    unsigned short* hs = xs;   // stride 136 now
    #pragma unroll
    for (int mt = 0; mt < 4; ++mt)
        #pragma unroll
        for (int r = 0; r < 4; ++r) {
            int row = mt * 16 + lq * 4 + r;
            hs[row * 136 + w * 32 + lc]      = f2b(fmaxf(acc0[mt][r] + be1a, 0.f));
            hs[row * 136 + w * 32 + 16 + lc] = f2b(fmaxf(acc1v[mt][r] + be1b, 0.f));
        }
    __syncthreads();

    // GEMM2 (untransposed): [64,128] @ We2[128,64]; wave w owns N cols [w*16, w*16+16)
    // B-frags register-resident from We2T rows (B[k][n=lc], 8 consecutive k).
    bf16x8 b2[4];
    #pragma unroll
    for (int c = 0; c < 4; ++c)
        b2[c] = *(const bf16x8*)&We2T[(size_t)(w * 16 + lc) * 128 + c * 32 + lq * 8];
    const float be2v = be2[w * 16 + lc];

    f32x4 acc2[4];
    #pragma unroll
    for (int mt = 0; mt < 4; ++mt) acc2[mt] = (f32x4)0.f;
    #pragma unroll
    for (int c = 0; c < 4; ++c) {
        #pragma unroll
        for (int mt = 0; mt < 4; ++mt) {
            bf16x8 a = *(const bf16x8*)&hs[(mt * 16 + lc) * 136 + c * 32 + lq * 8];
            acc2[mt] = MFMA16(a, b2[c], acc2[mt], 0, 0, 0);
        }
    }

    // scatter: element (row = mt*16+lq*4+r, col = w*16+lc) -> fp32 atomicAdd
    // 16 lanes (lc) per (mt,r,lq) write 64 consecutive bytes -> coalesced.
    const int col = w * 16 + lc;
    #pragma unroll
    for (int mt = 0; mt < 4; ++mt)
        #pragma unroll
        for (int r = 0; r < 4; ++r) {
            int row = mt * 16 + lq * 4 + r;
            atomicAdd(&agg[(size_t)ridx[row] * 64 + col], acc2[mt][r] + be2v);
        }
}

// ---------------- node kernel: 64 nodes/block ----------------
__global__ __launch_bounds__(256, 4) void node_kernel(
    const unsigned short* __restrict__ nodes_bf, const float* __restrict__ agg,
    const unsigned short* __restrict__ Wn1T, const float* __restrict__ bn1,
    const unsigned short* __restrict__ Wn2T, const float* __restrict__ bn2,
    float* __restrict__ out)
{
    __shared__ unsigned short xs[64 * 136];   // [agg|node] input, then hs (stride 136)

    const int t = threadIdx.x;
    const int n0 = blockIdx.x * 64;
    const int w = t >> 6, l = t & 63, lc = l & 15, lq = l >> 4;

    bf16x8 b1[4][2];
    #pragma unroll
    for (int c = 0; c < 4; ++c)
        #pragma unroll
        for (int j = 0; j < 2; ++j)
            b1[c][j] = *(const bf16x8*)&Wn1T[(size_t)(w * 32 + j * 16 + lc) * 128 + c * 32 + lq * 8];
    const float bn1a = bn1[w * 32 + lc];
    const float bn1b = bn1[w * 32 + 16 + lc];

    // stage agg (fp32 -> bf16), cols 0..63
    #pragma unroll
    for (int i = 0; i < 4; ++i) {
        int idx = t + 256 * i;               // 0..1023
        int m = idx >> 4, q = idx & 15;
        int n = n0 + m;
        float4 v = make_float4(0.f, 0.f, 0.f, 0.f);
        if (n < NN) v = *(const float4*)&agg[(size_t)n * 64 + q * 4];
        us4 o; o[0] = f2b(v.x); o[1] = f2b(v.y); o[2] = f2b(v.z); o[3] = f2b(v.w);
        *(us4*)&xs[m * 136 + q * 4] = o;
    }
    // stage node feats (bf16), cols 64..127
    us8 z = {0,0,0,0,0,0,0,0};
    #pragma unroll
    for (int i = 0; i < 2; ++i) {
        int idx = t + 256 * i;
        int m = idx >> 3, q = idx & 7;
        int n = n0 + m;
        us8 v = (n < NN) ? *(const us8*)&nodes_bf[(size_t)n * 64 + q * 8] : z;
        *(us8*)&xs[m * 136 + 64 + q * 8] = v;
    }
    __syncthreads();

    f32x4 acc0[4], acc1v[4];
    #pragma unroll
    for (int mt = 0; mt < 4; ++mt) { acc0[mt] = (f32x4)0.f; acc1v[mt] = (f32x4)0.f; }

    #pragma unroll
    for (int c = 0; c < 4; ++c) {
        #pragma unroll
        for (int mt = 0; mt < 4; ++mt) {
            bf16x8 a = *(const bf16x8*)&xs[(mt * 16 + lc) * 136 + c * 32 + lq * 8];
            acc0[mt]  = MFMA16(a, b1[c][0], acc0[mt], 0, 0, 0);
            acc1v[mt] = MFMA16(a, b1[c][1], acc1v[mt], 0, 0, 0);
        }
    }
    __syncthreads();

    unsigned short* hs = xs;
    #pragma unroll
    for (int mt = 0; mt < 4; ++mt)
        #pragma unroll
        for (int r = 0; r < 4; ++r) {
            int row = mt * 16 + lq * 4 + r;
            hs[row * 136 + w * 32 + lc]      = f2b(fmaxf(acc0[mt][r] + bn1a, 0.f));
            hs[row * 136 + w * 32 + 16 + lc] = f2b(fmaxf(acc1v[mt][r] + bn1b, 0.f));
        }
    __syncthreads();

    bf16x8 b2[4];
    #pragma unroll
    for (int c = 0; c < 4; ++c)
        b2[c] = *(const bf16x8*)&Wn2T[(size_t)(w * 16 + lc) * 128 + c * 32 + lq * 8];
    const float bn2v = bn2[w * 16 + lc];

    f32x4 acc2[4];
    #pragma unroll
    for (int mt = 0; mt < 4; ++mt) acc2[mt] = (f32x4)0.f;
    #pragma unroll
    for (int c = 0; c < 4; ++c) {
        #pragma unroll
        for (int mt = 0; mt < 4; ++mt) {
            bf16x8 a = *(const bf16x8*)&hs[(mt * 16 + lc) * 136 + c * 32 + lq * 8];
            acc2[mt] = MFMA16(a, b2[c], acc2[mt], 0, 0, 0);
        }
    }

    const int col = w * 16 + lc;
    #pragma unroll
    for (int mt = 0; mt < 4; ++mt)
        #pragma unroll
        for (int r = 0; r < 4; ++r) {
            int row = n0 + mt * 16 + lq * 4 + r;
            if (row < NN) out[(size_t)row * 64 + col] = acc2[mt][r] + bn2v;
        }
}

extern "C" void kernel_launch(void* const* d_in, const int* in_sizes, int n_in,
                              void* d_out, int out_size, void* d_ws, size_t ws_size,
                              hipStream_t stream) {
    const float* nodes = (const float*)d_in[0];
    const float* edges = (const float*)d_in[1];
    const float* We1   = (const float*)d_in[2];
    const float* be1   = (const float*)d_in[3];
    const float* We2   = (const float*)d_in[4];
    const float* be2   = (const float*)d_in[5];
    const float* Wn1   = (const float*)d_in[6];
    const float* bn1   = (const float*)d_in[7];
    const float* Wn2   = (const float*)d_in[8];
    const float* bn2   = (const float*)d_in[9];
    const int* senders   = (const int*)d_in[10];
    const int* receivers = (const int*)d_in[11];
    float* out = (float*)d_out;

    char* ws = (char*)d_ws;
    float* agg               = (float*)ws;                        // 12,800,000 B (fp32)
    unsigned short* nodes_bf = (unsigned short*)(ws + 12800000);  //  6,400,000 B
    unsigned short* We1T = (unsigned short*)(ws + 19200000);      //     49,152 B
    unsigned short* We2T = (unsigned short*)(ws + 19249152);      //     16,384 B
    unsigned short* Wn1T = (unsigned short*)(ws + 19265536);      //     32,768 B
    unsigned short* Wn2T = (unsigned short*)(ws + 19298304);      //     16,384 B

    hipMemsetAsync(agg, 0, (size_t)NN * 64 * sizeof(float), stream);
    prep_kernel<<<416, 256, 0, stream>>>(nodes, We1, We2, Wn1, Wn2,
                                         nodes_bf, We1T, We2T, Wn1T, Wn2T);
    edge_kernel<<<NE / 64, 256, 0, stream>>>(nodes_bf, edges, We1T, be1, We2T, be2,
                                             senders, receivers, agg);
    node_kernel<<<(NN + 63) / 64, 256, 0, stream>>>(nodes_bf, agg, Wn1T, bn1, Wn2T, bn2, out);
}